// Round 5
// baseline (112.051 us; speedup 1.0000x reference)
//
#include <hip/hip_runtime.h>

#define R 192
#define BATCH 1024
#define NTILE 24              // 24 i-tiles of 8 rooms
#define NSTRIPE 8
#define K2_BLOCKS (NSTRIPE * NTILE * 4)   // 768

// ws layout:
//   ws[0] = overlap accumulator   (zeroed by prep blk 114)
//   ws[1] = adjacency accumulator (zeroed by prep blk 114)
//   ws[2] = ticket counter u32    (zeroed by prep blk 114)
//   ws[4 .. 4+192)  = prep per-block MSE partials (96 x {mp,ms}), plain stores
//   byte 4096       = maskF[24][192][8] floats: 1.0f iff adj(8t+k, j)>0 && j>8t+k  (144 KB)
//   byte 262144     = roomA[r][b] float4 = (x, y, x+w, y+h)   (3 MB)
//   byte 262144+3MB = roomC[r][b] float2 = (cx, cy)           (1.5 MB)
#define MASKF_OFF_B 4096
#define ROOMA_OFF_B 262144
#define ROOMC_OFF_B (262144 + (3 << 20))

__global__ __launch_bounds__(256) void prep_kernel(
    const float* __restrict__ pos, const float* __restrict__ siz,
    const float* __restrict__ tpos, const float* __restrict__ tsiz,
    const int* __restrict__ adj, float* __restrict__ ws)
{
    const int blk = blockIdx.x;
    const int tid = threadIdx.x;

    if (blk < 96) {
        // ---- transpose + fused MSE partials ----
        __shared__ float wsum[4][2];
        float4* roomA = (float4*)((char*)ws + ROOMA_OFF_B);
        float2* roomC = (float2*)((char*)ws + ROOMC_OFF_B);
        const int bg = blk & 3;
        const int rt = blk >> 2;           // 0..23
        const int b  = bg * 256 + tid;

        const float2* pb  = (const float2*)pos  + (size_t)b * R;
        const float2* sb  = (const float2*)siz  + (size_t)b * R;
        const float2* tpb = (const float2*)tpos + (size_t)b * R;
        const float2* tsb = (const float2*)tsiz + (size_t)b * R;

        float mp = 0.0f, ms = 0.0f;
        #pragma unroll
        for (int k = 0; k < 8; ++k) {
            const int r = rt * 8 + k;
            float2 p  = pb[r];
            float2 s  = sb[r];
            float2 tp = tpb[r];
            float2 ts = tsb[r];
            float dpx = p.x - tp.x, dpy = p.y - tp.y;
            float dsx = s.x - ts.x, dsy = s.y - ts.y;
            mp += dpx * dpx + dpy * dpy;
            ms += dsx * dsx + dsy * dsy;
            roomA[r * BATCH + b] = make_float4(p.x, p.y, p.x + s.x, p.y + s.y);
            roomC[r * BATCH + b] = make_float2(fmaf(0.5f, s.x, p.x), fmaf(0.5f, s.y, p.y));
        }
        for (int off = 32; off > 0; off >>= 1) {
            mp += __shfl_down(mp, off);
            ms += __shfl_down(ms, off);
        }
        const int wid = tid >> 6, lane = tid & 63;
        if (lane == 0) { wsum[wid][0] = mp; wsum[wid][1] = ms; }
        __syncthreads();
        if (tid == 0) {
            ws[4 + blk * 2]     = wsum[0][0] + wsum[1][0] + wsum[2][0] + wsum[3][0];
            ws[4 + blk * 2 + 1] = wsum[0][1] + wsum[1][1] + wsum[2][1] + wsum[3][1];
        }
    } else if (blk < 114) {
        // ---- float mask table: maskF[t][j][k] ----
        float* maskF = (float*)((char*)ws + MASKF_OFF_B);
        const int e = (blk - 96) * 256 + tid;       // 0 .. 4607
        const int t = e / R;
        const int j = e - t * R;
        float f[8];
        #pragma unroll
        for (int k = 0; k < 8; ++k) {
            const int i = 8 * t + k;
            f[k] = ((adj[i * R + j] > 0) && (j > i)) ? 1.0f : 0.0f;
        }
        float4* dst = (float4*)(maskF + (size_t)e * 8);
        dst[0] = make_float4(f[0], f[1], f[2], f[3]);
        dst[1] = make_float4(f[4], f[5], f[6], f[7]);
    } else {
        // ---- zero accumulators + ticket ----
        if (tid < 4) ws[tid] = 0.0f;
    }
}

__global__ __launch_bounds__(256) void pairs_kernel(float* __restrict__ ws,
                                                    float* __restrict__ out)
{
    __shared__ float wsum[4][2];
    __shared__ int is_last;

    const float4* __restrict__ roomA = (const float4*)((const char*)ws + ROOMA_OFF_B);
    const float2* __restrict__ roomC = (const float2*)((const char*)ws + ROOMC_OFF_B);
    const float*  __restrict__ maskF = (const float*)((const char*)ws + MASKF_OFF_B);

    const int s   = blockIdx.x;           // 0..7  j-stripe
    const int t   = blockIdx.y;           // 0..23 i-tile
    const int bg  = blockIdx.z;           // 0..3  batch group
    const int tid = threadIdx.x;
    const int b   = bg * 256 + tid;
    const int i0  = 8 * t;

    // i-side operands in registers
    float4 A[8];
    float2 C[8];
    #pragma unroll
    for (int k = 0; k < 8; ++k) {
        A[k] = roomA[(i0 + k) * BATCH + b];
        C[k] = roomC[(i0 + k) * BATCH + b];
    }

    float ov = 0.0f, ad = 0.0f;

    // Uniform trip count: j = i0+8+s, i0+16+s, ... ; exactly (23-t) iterations.
    const int trip = 23 - t;
    const float4* pA = roomA + (size_t)(i0 + 8 + s) * BATCH + b;
    const float2* pC = roomC + (size_t)(i0 + 8 + s) * BATCH + b;
    const float4* pM = (const float4*)(maskF + (size_t)(t * R + i0 + 8 + s) * 8);

    for (int it = 0; it < trip; ++it) {
        const float4 rb = pA[0];
        const float2 rc = pC[0];
        const float4 m0 = pM[0];
        const float4 m1 = pM[1];
        float fm[8];
        *(float4*)&fm[0] = m0;
        *(float4*)&fm[4] = m1;
        #pragma unroll
        for (int k = 0; k < 8; ++k) {
            float ow = fminf(A[k].z, rb.z) - fmaxf(A[k].x, rb.x);
            float oh = fminf(A[k].w, rb.w) - fmaxf(A[k].y, rb.y);
            ov = fmaf(fmaxf(ow, 0.0f), fmaxf(oh, 0.0f), ov);
            float dx = C[k].x - rc.x;
            float dy = C[k].y - rc.y;
            float d  = __builtin_amdgcn_sqrtf(fmaf(dx, dx, dy * dy));
            ad = fmaf(fm[k], d, ad);      // branchless: mask is 0.0/1.0
        }
        pA += (size_t)NSTRIPE * BATCH;
        pC += (size_t)NSTRIPE * BATCH;
        pM += NSTRIPE * 2;
    }

    if (s == 0) {
        // intra-tile triangle (28 pairs), operands in registers, branchless
        #pragma unroll
        for (int k2 = 1; k2 < 8; ++k2) {
            #pragma unroll
            for (int k1 = 0; k1 < k2; ++k1) {
                float mf = maskF[(size_t)(t * R + i0 + k2) * 8 + k1];
                float ow = fminf(A[k1].z, A[k2].z) - fmaxf(A[k1].x, A[k2].x);
                float oh = fminf(A[k1].w, A[k2].w) - fmaxf(A[k1].y, A[k2].y);
                ov = fmaf(fmaxf(ow, 0.0f), fmaxf(oh, 0.0f), ov);
                float dx = C[k1].x - C[k2].x;
                float dy = C[k1].y - C[k2].y;
                float d  = __builtin_amdgcn_sqrtf(fmaf(dx, dx, dy * dy));
                ad = fmaf(mf, d, ad);
            }
        }
    }

    // block reduction
    for (int off = 32; off > 0; off >>= 1) {
        ov += __shfl_down(ov, off);
        ad += __shfl_down(ad, off);
    }
    const int wid = tid >> 6, lane = tid & 63;
    if (lane == 0) { wsum[wid][0] = ov; wsum[wid][1] = ad; }
    __syncthreads();
    if (tid == 0) {
        float o = wsum[0][0] + wsum[1][0] + wsum[2][0] + wsum[3][0];
        float a = wsum[0][1] + wsum[1][1] + wsum[2][1] + wsum[3][1];
        atomicAdd(&ws[0], o);
        atomicAdd(&ws[1], a);
        __threadfence();
        unsigned int old = atomicAdd((unsigned int*)(ws + 2), 1u);
        is_last = (old == (unsigned int)(K2_BLOCKS - 1)) ? 1 : 0;
    }
    __syncthreads();

    if (is_last) {
        // fused finalize
        float mp = (tid < 96) ? ws[4 + 2 * tid]     : 0.0f;
        float ms = (tid < 96) ? ws[4 + 2 * tid + 1] : 0.0f;
        for (int off = 32; off > 0; off >>= 1) {
            mp += __shfl_down(mp, off);
            ms += __shfl_down(ms, off);
        }
        if (lane == 0) { wsum[wid][0] = mp; wsum[wid][1] = ms; }
        __syncthreads();
        if (tid == 0) {
            float mseP = wsum[0][0] + wsum[1][0] + wsum[2][0] + wsum[3][0];
            float mseS = wsum[0][1] + wsum[1][1] + wsum[2][1] + wsum[3][1];
            float ovT  = atomicAdd(&ws[0], 0.0f);
            float adT  = atomicAdd(&ws[1], 0.0f);
            const float invN = 1.0f / (float)(BATCH * R * 2);
            const float invB = 1.0f / (float)BATCH;
            float pos_loss  = mseP * invN;
            float size_loss = mseS * invN;
            float overlap   = ovT * invB;
            float adjl      = adT * invB;
            out[0] = pos_loss + size_loss + 0.5f * overlap + 0.3f * adjl;
            out[1] = pos_loss;
            out[2] = size_loss;
            out[3] = overlap;
            out[4] = adjl;
        }
    }
}

extern "C" void kernel_launch(void* const* d_in, const int* in_sizes, int n_in,
                              void* d_out, int out_size, void* d_ws, size_t ws_size,
                              hipStream_t stream) {
    const float* pos  = (const float*)d_in[0];
    const float* siz  = (const float*)d_in[1];
    const float* tpos = (const float*)d_in[2];
    const float* tsiz = (const float*)d_in[3];
    const int*   adj  = (const int*)d_in[4];
    float* ws  = (float*)d_ws;
    float* out = (float*)d_out;

    hipLaunchKernelGGL(prep_kernel, dim3(115), dim3(256), 0, stream,
                       pos, siz, tpos, tsiz, adj, ws);
    hipLaunchKernelGGL(pairs_kernel, dim3(NSTRIPE, NTILE, 4), dim3(256), 0, stream,
                       ws, out);
}